// Round 3
// baseline (246.740 us; speedup 1.0000x reference)
//
#include <hip/hip_runtime.h>
#include <hip/hip_bf16.h>
#include <math.h>

#define NB 512
#define NS 200
#define NH 256
#define TILE_S 32
#define LDSPAD 8
#define LDW (NH + LDSPAD)        // 264 f16 row stride
#define WS_STRIDE 258            // per (b,half): [m, Z, pooled[256]]
#define NPART (NB * 2)           // 1024 partial blocks

// ws float-offset layout
#define OFF_PART 0
#define OFF_L    (NPART * WS_STRIDE)              // partials: 1024*258 floats
#define OFF_UB   (OFF_L + NB * NH)                // l: 512*256 floats
#define WS_FLOATS_PRE  (OFF_UB + (NH * NH) / 2)   // + U-fp16 swizzled (32768 floats) = 1.71 MB

typedef _Float16 f16x8 __attribute__((ext_vector_type(8)));
typedef float    f32x4 __attribute__((ext_vector_type(4)));

// DPP-based xor/rotate add within each 16-lane row (VALU, not LDS port).
template<int CTRL>
__device__ __forceinline__ float dpp_xadd(float v) {
  return v + __int_as_float(
      __builtin_amdgcn_update_dpp(0, __float_as_int(v), CTRL, 0xf, 0xf, true));
}
// full 16-lane sum: quad_perm[1,0,3,2]=0xB1, quad_perm[2,3,0,1]=0x4E,
// row_ror:4=0x124, row_ror:8=0x128
__device__ __forceinline__ float row16_sum(float v) {
  v = dpp_xadd<0xB1>(v);
  v = dpp_xadd<0x4E>(v);
  v = dpp_xadd<0x124>(v);
  v = dpp_xadd<0x128>(v);
  return v;
}

// ---------------- Kernel 0: precompute l = lastm@W^T (fp32) and swizzled fp16 U ----
__global__ __launch_bounds__(256)
void precompute(const float* __restrict__ lastm, const float* __restrict__ W,
                const float* __restrict__ U,
                float* __restrict__ l_ws, _Float16* __restrict__ Uswz)
{
  const int t = threadIdx.x;
  if (blockIdx.x < NB) {
    const int b = blockIdx.x;
    __shared__ float lm_sm[NH];
    lm_sm[t] = lastm[(size_t)b * NH + t];
    __syncthreads();
    const float4* wrow = (const float4*)(W + (size_t)t * NH);
    const float4* lrow = (const float4*)lm_sm;
    float a0 = 0.f, a1 = 0.f, a2 = 0.f, a3 = 0.f;
#pragma unroll 8
    for (int i = 0; i < NH / 4; ++i) {
      float4 w4 = wrow[i];
      float4 m4 = lrow[i];
      a0 = fmaf(w4.x, m4.x, a0);
      a1 = fmaf(w4.y, m4.y, a1);
      a2 = fmaf(w4.z, m4.z, a2);
      a3 = fmaf(w4.w, m4.w, a3);
    }
    l_ws[(size_t)b * NH + t] = (a0 + a1) + (a2 + a3);
  } else {
    const int id    = (blockIdx.x - NB) * 256 + t;   // 8192 frags
    const int n_blk = id >> 9;
    const int kk    = (id >> 6) & 7;
    const int lane  = id & 63;
    const int row   = n_blk * 16 + (lane & 15);
    const int col   = kk * 32 + (lane >> 4) * 8;
    const float4* s = (const float4*)(U + (size_t)row * NH + col);
    const float4 a = s[0], c = s[1];
    f16x8 pk;
    pk[0] = (_Float16)a.x; pk[1] = (_Float16)a.y;
    pk[2] = (_Float16)a.z; pk[3] = (_Float16)a.w;
    pk[4] = (_Float16)c.x; pk[5] = (_Float16)c.y;
    pk[6] = (_Float16)c.z; pk[7] = (_Float16)c.w;
    *(f16x8*)(Uswz + (size_t)id * 8) = pk;
  }
}

#define CVT_HL(idx, val) { const float x_ = (val); const _Float16 h_ = (_Float16)x_; \
                           ph[idx] = h_; pl[idx] = (_Float16)(x_ - (float)h_); }

// ---------------- Kernel 1: partial attention over an S-range ----------------
// 512 threads = 8 waves x 32 n-cols. Double-buffered hi/lo LDS + register
// prefetch of tile t+1's global loads (issued at loop top, written to the
// other buffer between the score barriers -> HBM latency hidden under
// MFMA+softmax). DPP reduce (VALU) replaces ds_swizzle shfl; pooled reads
// 2x b128 per thread (8 cols x 2 rows) instead of 16x u16.
template<bool PRE>
__global__ __launch_bounds__(512, 4)
void fused_meta_attn_part(const float* __restrict__ mem,    // [B,S,H]
                          const float* __restrict__ lastm,  // [B,H]
                          const float* __restrict__ U,      // [H,H] fp32 (fallback)
                          const float* __restrict__ W,      // [H,H] (fallback)
                          const float* __restrict__ V,      // [H]
                          const float* __restrict__ l_ws,   // [B,H] (PRE)
                          const _Float16* __restrict__ Uswz,// swizzled fp16 U (PRE)
                          float* __restrict__ part)         // [NPART, WS_STRIDE]
{
  const int b    = blockIdx.x >> 1;
  const int half = blockIdx.x & 1;
  const int s_begin = half ? 96 : 0;
  const int s_end   = half ? NS : 96;
  const int ntiles  = half ? 4 : 3;

  const int t     = threadIdx.x;   // 0..511
  const int wave  = t >> 6;        // 0..7: owns n-cols [wave*32, wave*32+32)
  const int lane  = t & 63;
  const int m16   = lane & 15;
  const int quad  = lane >> 4;
  const int g     = t >> 5;        // 0..15: pooled row-pair {2g, 2g+1}
  const int hblk  = (t & 31) * 8;  // pooled: 8 h-cols

  __shared__ __align__(16) _Float16 hi_sm[2][TILE_S][LDW];  // 33.8 KB
  __shared__ __align__(16) _Float16 lo_sm[2][TILE_S][LDW];  // 33.8 KB
  __shared__ float swave_sm[8][TILE_S];
  __shared__ float e_sm[TILE_S];
  __shared__ float mz_sm[2];

  // per-thread l/V for this wave's 2 n-fragments
  float l_reg[2], v_reg[2];
  if constexpr (!PRE) {
    __shared__ float l_sm[NH];
    __shared__ float lm_sm[NH];
    if (t < NH) lm_sm[t] = lastm[(size_t)b * NH + t];
    __syncthreads();
    if (t < NH) {
      const float4* wrow = (const float4*)(W + (size_t)t * NH);
      const float4* lrow = (const float4*)lm_sm;
      float a0 = 0.f, a1 = 0.f, a2 = 0.f, a3 = 0.f;
#pragma unroll 8
      for (int i = 0; i < NH / 4; ++i) {
        float4 w4 = wrow[i];
        float4 m4 = lrow[i];
        a0 = fmaf(w4.x, m4.x, a0);
        a1 = fmaf(w4.y, m4.y, a1);
        a2 = fmaf(w4.z, m4.z, a2);
        a3 = fmaf(w4.w, m4.w, a3);
      }
      l_sm[t] = (a0 + a1) + (a2 + a3);
    }
    __syncthreads();
#pragma unroll
    for (int nf = 0; nf < 2; ++nf)
      l_reg[nf] = l_sm[wave * 32 + nf * 16 + m16];
  } else {
#pragma unroll
    for (int nf = 0; nf < 2; ++nf)
      l_reg[nf] = l_ws[(size_t)b * NH + wave * 32 + nf * 16 + m16];
  }
#pragma unroll
  for (int nf = 0; nf < 2; ++nf)
    v_reg[nf] = V[wave * 32 + nf * 16 + m16];
  const float vsum  = v_reg[0] + v_reg[1];
  const float vm2_0 = -2.f * v_reg[0];
  const float vm2_1 = -2.f * v_reg[1];

  // ---- U B-fragments in registers for the whole kernel: 2 nf x 8 kk ----
  f16x8 u_frag[2][8];
  if constexpr (PRE) {
    const _Float16* uw = Uswz + ((size_t)(wave * 2 * 8 * 64) + lane) * 8;
#pragma unroll
    for (int nf = 0; nf < 2; ++nf)
#pragma unroll
      for (int kk = 0; kk < 8; ++kk)
        u_frag[nf][kk] = *(const f16x8*)(uw + (size_t)((nf * 8 + kk) << 9));
  } else {
#pragma unroll
    for (int nf = 0; nf < 2; ++nf) {
      const int n = wave * 32 + nf * 16 + m16;
      const float* urow = U + (size_t)n * NH;
#pragma unroll
      for (int kk = 0; kk < 8; ++kk) {
        const float4 lo = *(const float4*)(urow + kk * 32 + quad * 8);
        const float4 hi = *(const float4*)(urow + kk * 32 + quad * 8 + 4);
        f16x8 f;
        f[0] = (_Float16)lo.x; f[1] = (_Float16)lo.y;
        f[2] = (_Float16)lo.z; f[3] = (_Float16)lo.w;
        f[4] = (_Float16)hi.x; f[5] = (_Float16)hi.y;
        f[6] = (_Float16)hi.z; f[7] = (_Float16)hi.w;
        u_frag[nf][kk] = f;
      }
    }
  }

  // ---- prologue: stage tile 0 into buffer 0 (full 32 rows always) ----
  {
    const float4* src4 = (const float4*)(mem + ((size_t)b * NS + s_begin) * NH);
    const int f0 = t, f1 = 512 + t;
    const float4 a0 = src4[f0 * 2], a1 = src4[f0 * 2 + 1];
    const float4 b0 = src4[f1 * 2], b1 = src4[f1 * 2 + 1];
    {
      f16x8 ph, pl;
      CVT_HL(0, a0.x) CVT_HL(1, a0.y) CVT_HL(2, a0.z) CVT_HL(3, a0.w)
      CVT_HL(4, a1.x) CVT_HL(5, a1.y) CVT_HL(6, a1.z) CVT_HL(7, a1.w)
      *(f16x8*)&hi_sm[0][f0 >> 5][(f0 & 31) * 8] = ph;
      *(f16x8*)&lo_sm[0][f0 >> 5][(f0 & 31) * 8] = pl;
    }
    {
      f16x8 ph, pl;
      CVT_HL(0, b0.x) CVT_HL(1, b0.y) CVT_HL(2, b0.z) CVT_HL(3, b0.w)
      CVT_HL(4, b1.x) CVT_HL(5, b1.y) CVT_HL(6, b1.z) CVT_HL(7, b1.w)
      *(f16x8*)&hi_sm[0][f1 >> 5][(f1 & 31) * 8] = ph;
      *(f16x8*)&lo_sm[0][f1 >> 5][(f1 & 31) * 8] = pl;
    }
  }
  __syncthreads();

  float m_run = -INFINITY;
  float Z     = 0.f;
  float pooledv[8];
#pragma unroll
  for (int j = 0; j < 8; ++j) pooledv[j] = 0.f;

  for (int tile = 0; tile < ntiles; ++tile) {
    const int cur = tile & 1;
    const int nxt = cur ^ 1;
    const int s0  = s_begin + tile * TILE_S;
    const int rows = min(TILE_S, s_end - s0);
    const int rows_next = (tile + 1 < ntiles) ? min(TILE_S, s_end - (s0 + TILE_S)) : 0;

    // ---- prefetch issue for tile t+1 (regs; written to LDS after bar1) ----
    float4 p00, p01, p10, p11;
    const bool ld0 = (t >> 5) < rows_next;          // rows 0..15
    const bool ld1 = ((512 + t) >> 5) < rows_next;  // rows 16..31
    {
      const float4* nsrc = (const float4*)(mem + ((size_t)b * NS + s0 + TILE_S) * NH);
      if (ld0) { p00 = nsrc[t * 2];         p01 = nsrc[t * 2 + 1]; }
      if (ld1) { p10 = nsrc[(512 + t) * 2]; p11 = nsrc[(512 + t) * 2 + 1]; }
    }

    // ---- MFMA: 32 rows x 32 n-cols per wave; hi+lo into same acc ----
    f32x4 acc[2][2];
    const f32x4 fzero = {0.f, 0.f, 0.f, 0.f};
#pragma unroll
    for (int mt = 0; mt < 2; ++mt)
#pragma unroll
      for (int nf = 0; nf < 2; ++nf)
        acc[mt][nf] = fzero;

#pragma unroll
    for (int kk = 0; kk < 8; ++kk) {
      const int c = kk * 32 + quad * 8;
      f16x8 a0h = *(const f16x8*)&hi_sm[cur][m16][c];
      f16x8 a1h = *(const f16x8*)&hi_sm[cur][16 + m16][c];
      f16x8 a0l = *(const f16x8*)&lo_sm[cur][m16][c];
      f16x8 a1l = *(const f16x8*)&lo_sm[cur][16 + m16][c];
#pragma unroll
      for (int nf = 0; nf < 2; ++nf) {
        acc[0][nf] = __builtin_amdgcn_mfma_f32_16x16x32_f16(a0h, u_frag[nf][kk], acc[0][nf], 0, 0, 0);
        acc[1][nf] = __builtin_amdgcn_mfma_f32_16x16x32_f16(a1h, u_frag[nf][kk], acc[1][nf], 0, 0, 0);
        acc[0][nf] = __builtin_amdgcn_mfma_f32_16x16x32_f16(a0l, u_frag[nf][kk], acc[0][nf], 0, 0, 0);
        acc[1][nf] = __builtin_amdgcn_mfma_f32_16x16x32_f16(a1l, u_frag[nf][kk], acc[1][nf], 0, 0, 0);
      }
    }

    // ---- p = vsum + sum_nf (-2 v[nf]) / (e^{2x}+1)  (tanh identity) ----
    // then 16-lane DPP sum over m16 (the wave's n-columns), VALU only.
#pragma unroll
    for (int mt = 0; mt < 2; ++mt) {
#pragma unroll
      for (int reg = 0; reg < 4; ++reg) {
        const float x0 = acc[mt][0][reg] + l_reg[0];
        const float x1 = acc[mt][1][reg] + l_reg[1];
        const float e0 = __expf(x0 + x0);
        const float e1 = __expf(x1 + x1);
        float s = vsum;
        s += __fdividef(vm2_0, e0 + 1.f);
        s += __fdividef(vm2_1, e1 + 1.f);
        s = row16_sum(s);
        if (m16 == 0)
          swave_sm[wave][mt * 16 + quad * 4 + reg] = s;
      }
    }
    __syncthreads();  // bar1: swave ready; buffers from prev iter free

    // ---- wave0 lanes 0..31: scores -> m, e[], z (serial, overlapped below) ----
    if (t < TILE_S) {
      float s = swave_sm[0][t];
#pragma unroll
      for (int w = 1; w < 8; ++w) s += swave_sm[w][t];
      const float sv = (t < rows) ? s : -INFINITY;
      float mt_ = sv;
#pragma unroll
      for (int off = 1; off < 32; off <<= 1)
        mt_ = fmaxf(mt_, __shfl_xor(mt_, off));
      const float m_new = fmaxf(m_run, mt_);
      float e = (t < rows) ? __expf(sv - m_new) : 0.f;
      e_sm[t] = e;
      float z = e;
#pragma unroll
      for (int off = 1; off < 32; off <<= 1)
        z += __shfl_xor(z, off);
      if (t == 0) { mz_sm[0] = m_new; mz_sm[1] = z; }
    }

    // ---- all waves: convert prefetched tile t+1 and write the other buffer
    //      (overlaps wave0's serial phase; HBM latency already covered) ----
    if (ld0) {
      f16x8 ph, pl;
      CVT_HL(0, p00.x) CVT_HL(1, p00.y) CVT_HL(2, p00.z) CVT_HL(3, p00.w)
      CVT_HL(4, p01.x) CVT_HL(5, p01.y) CVT_HL(6, p01.z) CVT_HL(7, p01.w)
      *(f16x8*)&hi_sm[nxt][t >> 5][(t & 31) * 8] = ph;
      *(f16x8*)&lo_sm[nxt][t >> 5][(t & 31) * 8] = pl;
    }
    if (ld1) {
      f16x8 ph, pl;
      CVT_HL(0, p10.x) CVT_HL(1, p10.y) CVT_HL(2, p10.z) CVT_HL(3, p10.w)
      CVT_HL(4, p11.x) CVT_HL(5, p11.y) CVT_HL(6, p11.z) CVT_HL(7, p11.w)
      *(f16x8*)&hi_sm[nxt][(512 + t) >> 5][(t & 31) * 8] = ph;
      *(f16x8*)&lo_sm[nxt][(512 + t) >> 5][(t & 31) * 8] = pl;
    }
    __syncthreads();  // bar2: e_sm/mz ready

    // ---- pooled: thread owns 8 h-cols x 2 rows; 2x b128 + 2 broadcast b32 ----
    const float m_new = mz_sm[0];
    const float z_new = mz_sm[1];
    const float fac   = __expf(m_run - m_new);
    m_run = m_new;
    Z = fmaf(Z, fac, z_new);

    const float e0 = e_sm[2 * g];
    const float e1 = e_sm[2 * g + 1];
    const f16x8 r0 = *(const f16x8*)&hi_sm[cur][2 * g][hblk];
    const f16x8 r1 = *(const f16x8*)&hi_sm[cur][2 * g + 1][hblk];
#pragma unroll
    for (int j = 0; j < 8; ++j)
      pooledv[j] = fmaf(e0, (float)r0[j], fmaf(e1, (float)r1[j], pooledv[j] * fac));
    __syncthreads();  // bar3: pooled reads done before next iter's writes
  }

  // ---- combine 16 row-pair replicas via LDS tree (reuse hi_sm[0] as f32) ----
  float* scratch = (float*)&hi_sm[0][0][0];   // 16 x 264 f32 = 16896 B, fits exactly
  {
    f32x4 lo4 = {pooledv[0], pooledv[1], pooledv[2], pooledv[3]};
    f32x4 hi4 = {pooledv[4], pooledv[5], pooledv[6], pooledv[7]};
    *(f32x4*)&scratch[g * 264 + hblk]     = lo4;
    *(f32x4*)&scratch[g * 264 + hblk + 4] = hi4;
  }
  __syncthreads();
  float* base = part + (size_t)blockIdx.x * WS_STRIDE;
  if (t == 0) { base[0] = m_run; base[1] = Z; }
  if (t < NH) {
    float s = 0.f;
#pragma unroll
    for (int r = 0; r < 16; ++r)
      s += scratch[r * 264 + t];
    base[2 + t] = s;
  }
}

// ---------------- Kernel 2: merge halves + MetaW projection ----------------
__global__ __launch_bounds__(256)
void merge_project(const float* __restrict__ part,
                   const float* __restrict__ MetaW,  // [4,H]
                   const float* __restrict__ Metab,  // [4]
                   float* __restrict__ out)          // [B,4]
{
  const int b    = blockIdx.x;
  const int t    = threadIdx.x;
  const int wave = t >> 6;
  const int lane = t & 63;

  __shared__ float pooled_sm[NH];

  const float* b0 = part + (size_t)(b * 2)     * WS_STRIDE;
  const float* b1 = part + (size_t)(b * 2 + 1) * WS_STRIDE;
  const float m0 = b0[0], Z0 = b0[1];
  const float m1 = b1[0], Z1 = b1[1];
  const float mm = fmaxf(m0, m1);
  const float w0 = __expf(m0 - mm);
  const float w1 = __expf(m1 - mm);
  const float Zi = 1.f / (Z0 * w0 + Z1 * w1);

  pooled_sm[t] = (b0[2 + t] * w0 + b1[2 + t] * w1) * Zi;
  __syncthreads();

  float s = 0.f;
#pragma unroll
  for (int i = 0; i < 4; ++i) {
    const int h = i * 64 + lane;
    s = fmaf(pooled_sm[h], MetaW[(size_t)wave * NH + h], s);
  }
#pragma unroll
  for (int off = 32; off > 0; off >>= 1)
    s += __shfl_down(s, off);
  if (lane == 0)
    out[b * 4 + wave] = s + Metab[wave];
}

extern "C" void kernel_launch(void* const* d_in, const int* in_sizes, int n_in,
                              void* d_out, int out_size, void* d_ws, size_t ws_size,
                              hipStream_t stream) {
  const float* mem   = (const float*)d_in[0];
  const float* lastm = (const float*)d_in[1];
  const float* U     = (const float*)d_in[2];
  const float* W     = (const float*)d_in[3];
  const float* V     = (const float*)d_in[4];
  const float* MetaW = (const float*)d_in[5];
  const float* Metab = (const float*)d_in[6];
  float* out = (float*)d_out;
  float* ws  = (float*)d_ws;

  float* part = ws + OFF_PART;

  if (ws_size >= (size_t)WS_FLOATS_PRE * sizeof(float)) {
    float*    l_ws = ws + OFF_L;
    _Float16* Uswz = (_Float16*)(ws + OFF_UB);
    hipLaunchKernelGGL(precompute, dim3(NB + 32), dim3(256), 0, stream,
                       lastm, W, U, l_ws, Uswz);
    hipLaunchKernelGGL(fused_meta_attn_part<true>, dim3(NPART), dim3(512), 0, stream,
                       mem, lastm, U, W, V, l_ws, Uswz, part);
  } else {
    hipLaunchKernelGGL(fused_meta_attn_part<false>, dim3(NPART), dim3(512), 0, stream,
                       mem, lastm, U, W, V, (const float*)nullptr, (const _Float16*)nullptr, part);
  }
  hipLaunchKernelGGL(merge_project, dim3(NB), dim3(256), 0, stream,
                     part, MetaW, Metab, out);
}

// Round 5
// 230.503 us; speedup vs baseline: 1.0704x; 1.0704x over previous
//
#include <hip/hip_runtime.h>
#include <hip/hip_bf16.h>
#include <math.h>

#define NB 512
#define NS 200
#define NH 256
#define TILE_S 32
#define LDSPAD 8
#define LDW (NH + LDSPAD)        // 264 f16 row stride

// ws float-offset layout
#define OFF_SCORES 0                               // 512*200 floats = 400 KB
#define OFF_L    (NB * NS)                         // l: 512*256 floats
#define OFF_UB   (OFF_L + NB * NH)                 // U-fp16 swizzled (32768 floats)
#define WS_FLOATS_PRE  (OFF_UB + (NH * NH) / 2)

typedef _Float16 f16x8 __attribute__((ext_vector_type(8)));
typedef float    f32x4 __attribute__((ext_vector_type(4)));

// DPP-based add within each 16-lane row (VALU, not LDS port).
template<int CTRL>
__device__ __forceinline__ float dpp_xadd(float v) {
  return v + __int_as_float(
      __builtin_amdgcn_update_dpp(0, __float_as_int(v), CTRL, 0xf, 0xf, true));
}
// full 16-lane sum: quad_perm[1,0,3,2]=0xB1, quad_perm[2,3,0,1]=0x4E,
// row_ror:4=0x124, row_ror:8=0x128  (HW-verified in R2)
__device__ __forceinline__ float row16_sum(float v) {
  v = dpp_xadd<0xB1>(v);
  v = dpp_xadd<0x4E>(v);
  v = dpp_xadd<0x124>(v);
  v = dpp_xadd<0x128>(v);
  return v;
}

// ---------------- Kernel 0: precompute l = lastm@W^T (fp32) and swizzled fp16 U ----
__global__ __launch_bounds__(256)
void precompute(const float* __restrict__ lastm, const float* __restrict__ W,
                const float* __restrict__ U,
                float* __restrict__ l_ws, _Float16* __restrict__ Uswz)
{
  const int t = threadIdx.x;
  if (blockIdx.x < NB) {
    const int b = blockIdx.x;
    __shared__ float lm_sm[NH];
    lm_sm[t] = lastm[(size_t)b * NH + t];
    __syncthreads();
    const float4* wrow = (const float4*)(W + (size_t)t * NH);
    const float4* lrow = (const float4*)lm_sm;
    float a0 = 0.f, a1 = 0.f, a2 = 0.f, a3 = 0.f;
#pragma unroll 8
    for (int i = 0; i < NH / 4; ++i) {
      float4 w4 = wrow[i];
      float4 m4 = lrow[i];
      a0 = fmaf(w4.x, m4.x, a0);
      a1 = fmaf(w4.y, m4.y, a1);
      a2 = fmaf(w4.z, m4.z, a2);
      a3 = fmaf(w4.w, m4.w, a3);
    }
    l_ws[(size_t)b * NH + t] = (a0 + a1) + (a2 + a3);
  } else {
    const int id    = (blockIdx.x - NB) * 256 + t;   // 8192 frags
    const int n_blk = id >> 9;
    const int kk    = (id >> 6) & 7;
    const int lane  = id & 63;
    const int row   = n_blk * 16 + (lane & 15);
    const int col   = kk * 32 + (lane >> 4) * 8;
    const float4* s = (const float4*)(U + (size_t)row * NH + col);
    const float4 a = s[0], c = s[1];
    f16x8 pk;
    pk[0] = (_Float16)a.x; pk[1] = (_Float16)a.y;
    pk[2] = (_Float16)a.z; pk[3] = (_Float16)a.w;
    pk[4] = (_Float16)c.x; pk[5] = (_Float16)c.y;
    pk[6] = (_Float16)c.z; pk[7] = (_Float16)c.w;
    *(f16x8*)(Uswz + (size_t)id * 8) = pk;
  }
}

#define CVT_HL(idx, val) { const float x_ = (val); const _Float16 h_ = (_Float16)x_; \
                           ph[idx] = h_; pl[idx] = (_Float16)(x_ - (float)h_); }

// ---------------- Kernel A: scores[b,s] = V . tanh(mem[b,s]@U^T + l[b]) ----------
// 512 threads = 8 waves x 32 n-cols. Single-buffer hi/lo LDS + register prefetch
// of tile t+1 (16 VGPR) -> HBM latency hidden under MFMA+tanh. Only 2 barriers
// per tile; no pooled/softmax state resident (that's kernel B) so the live set
// (u_frag 64 + acc 16 + pf 16 + misc) fits the (512,4) 128-VGPR cap w/o spill.
template<bool PRE>
__global__ __launch_bounds__(512, 4)
void scores_part(const float* __restrict__ mem,    // [B,S,H]
                 const float* __restrict__ lastm,  // [B,H]
                 const float* __restrict__ U,      // [H,H] fp32 (fallback)
                 const float* __restrict__ W,      // [H,H] (fallback)
                 const float* __restrict__ V,      // [H]
                 const float* __restrict__ l_ws,   // [B,H] (PRE)
                 const _Float16* __restrict__ Uswz,// swizzled fp16 U (PRE)
                 float* __restrict__ scores)       // [B,S]
{
  const int b    = blockIdx.x >> 1;
  const int half = blockIdx.x & 1;
  const int s_begin = half ? 96 : 0;
  const int s_end   = half ? NS : 96;
  const int ntiles  = half ? 4 : 3;

  const int t     = threadIdx.x;   // 0..511
  const int wave  = t >> 6;        // 0..7: owns n-cols [wave*32, wave*32+32)
  const int lane  = t & 63;
  const int m16   = lane & 15;
  const int quad  = lane >> 4;

  __shared__ __align__(16) _Float16 hi_sm[TILE_S][LDW];  // 16.9 KB
  __shared__ __align__(16) _Float16 lo_sm[TILE_S][LDW];  // 16.9 KB
  __shared__ float swave_sm[8][TILE_S];

  // per-thread l/V for this wave's 2 n-fragments
  float l_reg[2], v_reg[2];
  if constexpr (!PRE) {
    __shared__ float l_sm[NH];
    __shared__ float lm_sm[NH];
    if (t < NH) lm_sm[t] = lastm[(size_t)b * NH + t];
    __syncthreads();
    if (t < NH) {
      const float4* wrow = (const float4*)(W + (size_t)t * NH);
      const float4* lrow = (const float4*)lm_sm;
      float a0 = 0.f, a1 = 0.f, a2 = 0.f, a3 = 0.f;
#pragma unroll 8
      for (int i = 0; i < NH / 4; ++i) {
        float4 w4 = wrow[i];
        float4 m4 = lrow[i];
        a0 = fmaf(w4.x, m4.x, a0);
        a1 = fmaf(w4.y, m4.y, a1);
        a2 = fmaf(w4.z, m4.z, a2);
        a3 = fmaf(w4.w, m4.w, a3);
      }
      l_sm[t] = (a0 + a1) + (a2 + a3);
    }
    __syncthreads();
#pragma unroll
    for (int nf = 0; nf < 2; ++nf)
      l_reg[nf] = l_sm[wave * 32 + nf * 16 + m16];
  } else {
#pragma unroll
    for (int nf = 0; nf < 2; ++nf)
      l_reg[nf] = l_ws[(size_t)b * NH + wave * 32 + nf * 16 + m16];
  }
#pragma unroll
  for (int nf = 0; nf < 2; ++nf)
    v_reg[nf] = V[wave * 32 + nf * 16 + m16];
  const float vsum  = v_reg[0] + v_reg[1];
  const float vm2_0 = -2.f * v_reg[0];
  const float vm2_1 = -2.f * v_reg[1];

  // ---- U B-fragments in registers for the whole kernel: 2 nf x 8 kk = 64 VGPR ----
  f16x8 u_frag[2][8];
  if constexpr (PRE) {
    const _Float16* uw = Uswz + ((size_t)(wave * 2 * 8 * 64) + lane) * 8;
#pragma unroll
    for (int nf = 0; nf < 2; ++nf)
#pragma unroll
      for (int kk = 0; kk < 8; ++kk)
        u_frag[nf][kk] = *(const f16x8*)(uw + (size_t)((nf * 8 + kk) << 9));
  } else {
#pragma unroll
    for (int nf = 0; nf < 2; ++nf) {
      const int n = wave * 32 + nf * 16 + m16;
      const float* urow = U + (size_t)n * NH;
#pragma unroll
      for (int kk = 0; kk < 8; ++kk) {
        const float4 lo = *(const float4*)(urow + kk * 32 + quad * 8);
        const float4 hi = *(const float4*)(urow + kk * 32 + quad * 8 + 4);
        f16x8 f;
        f[0] = (_Float16)lo.x; f[1] = (_Float16)lo.y;
        f[2] = (_Float16)lo.z; f[3] = (_Float16)lo.w;
        f[4] = (_Float16)hi.x; f[5] = (_Float16)hi.y;
        f[6] = (_Float16)hi.z; f[7] = (_Float16)hi.w;
        u_frag[nf][kk] = f;
      }
    }
  }

  // ---- prologue: stage tile 0 (full 32 rows always valid) ----
  {
    const float4* src4 = (const float4*)(mem + ((size_t)b * NS + s_begin) * NH);
    const int f0 = t, f1 = 512 + t;
    const float4 a0 = src4[f0 * 2], a1 = src4[f0 * 2 + 1];
    const float4 b0 = src4[f1 * 2], b1 = src4[f1 * 2 + 1];
    {
      f16x8 ph, pl;
      CVT_HL(0, a0.x) CVT_HL(1, a0.y) CVT_HL(2, a0.z) CVT_HL(3, a0.w)
      CVT_HL(4, a1.x) CVT_HL(5, a1.y) CVT_HL(6, a1.z) CVT_HL(7, a1.w)
      *(f16x8*)&hi_sm[f0 >> 5][(f0 & 31) * 8] = ph;
      *(f16x8*)&lo_sm[f0 >> 5][(f0 & 31) * 8] = pl;
    }
    {
      f16x8 ph, pl;
      CVT_HL(0, b0.x) CVT_HL(1, b0.y) CVT_HL(2, b0.z) CVT_HL(3, b0.w)
      CVT_HL(4, b1.x) CVT_HL(5, b1.y) CVT_HL(6, b1.z) CVT_HL(7, b1.w)
      *(f16x8*)&hi_sm[f1 >> 5][(f1 & 31) * 8] = ph;
      *(f16x8*)&lo_sm[f1 >> 5][(f1 & 31) * 8] = pl;
    }
  }
  __syncthreads();

  for (int tile = 0; tile < ntiles; ++tile) {
    const int s0 = s_begin + tile * TILE_S;
    const int rows_next = (tile + 1 < ntiles) ? min(TILE_S, s_end - (s0 + TILE_S)) : 0;

    // ---- prefetch issue for tile t+1 (regs; written to LDS after the barrier) ----
    float4 p00, p01, p10, p11;
    const bool ld0 = (t >> 5) < rows_next;          // rows 0..15
    const bool ld1 = ((512 + t) >> 5) < rows_next;  // rows 16..31
    {
      const float4* nsrc = (const float4*)(mem + ((size_t)b * NS + s0 + TILE_S) * NH);
      if (ld0) { p00 = nsrc[t * 2];         p01 = nsrc[t * 2 + 1]; }
      if (ld1) { p10 = nsrc[(512 + t) * 2]; p11 = nsrc[(512 + t) * 2 + 1]; }
    }

    // ---- MFMA: 32 rows x 32 n-cols per wave; hi+lo into same acc ----
    f32x4 acc[2][2];
    const f32x4 fzero = {0.f, 0.f, 0.f, 0.f};
#pragma unroll
    for (int mt = 0; mt < 2; ++mt)
#pragma unroll
      for (int nf = 0; nf < 2; ++nf)
        acc[mt][nf] = fzero;

#pragma unroll
    for (int kk = 0; kk < 8; ++kk) {
      const int c = kk * 32 + quad * 8;
      f16x8 a0h = *(const f16x8*)&hi_sm[m16][c];
      f16x8 a1h = *(const f16x8*)&hi_sm[16 + m16][c];
      f16x8 a0l = *(const f16x8*)&lo_sm[m16][c];
      f16x8 a1l = *(const f16x8*)&lo_sm[16 + m16][c];
#pragma unroll
      for (int nf = 0; nf < 2; ++nf) {
        acc[0][nf] = __builtin_amdgcn_mfma_f32_16x16x32_f16(a0h, u_frag[nf][kk], acc[0][nf], 0, 0, 0);
        acc[1][nf] = __builtin_amdgcn_mfma_f32_16x16x32_f16(a1h, u_frag[nf][kk], acc[1][nf], 0, 0, 0);
        acc[0][nf] = __builtin_amdgcn_mfma_f32_16x16x32_f16(a0l, u_frag[nf][kk], acc[0][nf], 0, 0, 0);
        acc[1][nf] = __builtin_amdgcn_mfma_f32_16x16x32_f16(a1l, u_frag[nf][kk], acc[1][nf], 0, 0, 0);
      }
    }

    // ---- p = vsum + sum_nf (-2 v[nf]) / (e^{2x}+1) (tanh identity), DPP n-reduce ----
#pragma unroll
    for (int mt = 0; mt < 2; ++mt) {
#pragma unroll
      for (int reg = 0; reg < 4; ++reg) {
        const float x0 = acc[mt][0][reg] + l_reg[0];
        const float x1 = acc[mt][1][reg] + l_reg[1];
        const float e0 = __expf(x0 + x0);
        const float e1 = __expf(x1 + x1);
        float s = vsum;
        s += __fdividef(vm2_0, e0 + 1.f);
        s += __fdividef(vm2_1, e1 + 1.f);
        s = row16_sum(s);
        if (m16 == 0)
          swave_sm[wave][mt * 16 + quad * 4 + reg] = s;
      }
    }
    __syncthreads();  // swave ready; all LDS reads of current tile done

    // ---- score write (32 lanes) || staging write of tile t+1 (all waves) ----
    if (t < TILE_S) {
      const int s_idx = s0 + t;
      if (s_idx < s_end) {
        float s = swave_sm[0][t];
#pragma unroll
        for (int w = 1; w < 8; ++w) s += swave_sm[w][t];
        scores[(size_t)b * NS + s_idx] = s;
      }
    }
    if (ld0) {
      f16x8 ph, pl;
      CVT_HL(0, p00.x) CVT_HL(1, p00.y) CVT_HL(2, p00.z) CVT_HL(3, p00.w)
      CVT_HL(4, p01.x) CVT_HL(5, p01.y) CVT_HL(6, p01.z) CVT_HL(7, p01.w)
      *(f16x8*)&hi_sm[t >> 5][(t & 31) * 8] = ph;
      *(f16x8*)&lo_sm[t >> 5][(t & 31) * 8] = pl;
    }
    if (ld1) {
      f16x8 ph, pl;
      CVT_HL(0, p10.x) CVT_HL(1, p10.y) CVT_HL(2, p10.z) CVT_HL(3, p10.w)
      CVT_HL(4, p11.x) CVT_HL(5, p11.y) CVT_HL(6, p11.z) CVT_HL(7, p11.w)
      *(f16x8*)&hi_sm[(512 + t) >> 5][(t & 31) * 8] = ph;
      *(f16x8*)&lo_sm[(512 + t) >> 5][(t & 31) * 8] = pl;
    }
    __syncthreads();  // next tile staged
  }
}

// ---------------- Kernel B: softmax(scores) -> pooled (fp32 mem) -> project ----
__global__ __launch_bounds__(512)
void softmax_pool_project(const float* __restrict__ scores, // [B,S]
                          const float* __restrict__ mem,    // [B,S,H]
                          const float* __restrict__ MetaW,  // [4,H]
                          const float* __restrict__ Metab,  // [4]
                          float* __restrict__ out)          // [B,4]
{
  const int b    = blockIdx.x;
  const int t    = threadIdx.x;   // 0..511
  const int wave = t >> 6;
  const int lane = t & 63;

  __shared__ float alpha_sm[256];
  __shared__ float red_sm[8];
  __shared__ __align__(16) float comb_sm[8][NH];
  __shared__ float pooled_sm[NH];

  // scores -> LDS
  float sv = -INFINITY;
  if (t < NS) sv = scores[(size_t)b * NS + t];
  if (t < 256) alpha_sm[t] = sv;

  // block max
  float mv = sv;
#pragma unroll
  for (int off = 1; off < 64; off <<= 1)
    mv = fmaxf(mv, __shfl_xor(mv, off));
  if (lane == 0) red_sm[wave] = mv;
  __syncthreads();
  float m = red_sm[0];
#pragma unroll
  for (int w = 1; w < 8; ++w) m = fmaxf(m, red_sm[w]);

  // e + block sum
  const float e = (t < NS) ? __expf(sv - m) : 0.f;
  float zv = e;
#pragma unroll
  for (int off = 1; off < 64; off <<= 1)
    zv += __shfl_xor(zv, off);
  __syncthreads();          // red_sm reuse
  if (lane == 0) red_sm[wave] = zv;
  if (t < 256) alpha_sm[t] = e;
  __syncthreads();
  float Z = red_sm[0];
#pragma unroll
  for (int w = 1; w < 8; ++w) Z += red_sm[w];
  const float Zi = 1.f / Z;

  // pooled: row-group rg = t>>6 handles rows s = rg, rg+8, ...; cols (t&63)*4
  const int rg = wave;
  const float4* m4 = (const float4*)(mem + (size_t)b * NS * NH);
  f32x4 acc = {0.f, 0.f, 0.f, 0.f};
#pragma unroll 5
  for (int s = rg; s < NS; s += 8) {
    const float a = alpha_sm[s];
    const float4 x = m4[s * 64 + lane];
    acc[0] = fmaf(a, x.x, acc[0]);
    acc[1] = fmaf(a, x.y, acc[1]);
    acc[2] = fmaf(a, x.z, acc[2]);
    acc[3] = fmaf(a, x.w, acc[3]);
  }
  *(f32x4*)&comb_sm[rg][lane * 4] = acc;
  __syncthreads();

  if (t < NH) {
    float p = 0.f;
#pragma unroll
    for (int r = 0; r < 8; ++r) p += comb_sm[r][t];
    pooled_sm[t] = p * Zi;
  }
  __syncthreads();

  // project: waves 0..3 -> out rows
  if (t < 256) {
    float s = 0.f;
#pragma unroll
    for (int i = 0; i < 4; ++i) {
      const int h = i * 64 + lane;
      s = fmaf(pooled_sm[h], MetaW[(size_t)wave * NH + h], s);
    }
#pragma unroll
    for (int off = 32; off > 0; off >>= 1)
      s += __shfl_down(s, off);
    if (lane == 0)
      out[b * 4 + wave] = s + Metab[wave];
  }
}

extern "C" void kernel_launch(void* const* d_in, const int* in_sizes, int n_in,
                              void* d_out, int out_size, void* d_ws, size_t ws_size,
                              hipStream_t stream) {
  const float* mem   = (const float*)d_in[0];
  const float* lastm = (const float*)d_in[1];
  const float* U     = (const float*)d_in[2];
  const float* W     = (const float*)d_in[3];
  const float* V     = (const float*)d_in[4];
  const float* MetaW = (const float*)d_in[5];
  const float* Metab = (const float*)d_in[6];
  float* out = (float*)d_out;
  float* ws  = (float*)d_ws;

  float* scores = ws + OFF_SCORES;

  if (ws_size >= (size_t)WS_FLOATS_PRE * sizeof(float)) {
    float*    l_ws = ws + OFF_L;
    _Float16* Uswz = (_Float16*)(ws + OFF_UB);
    hipLaunchKernelGGL(precompute, dim3(NB + 32), dim3(256), 0, stream,
                       lastm, W, U, l_ws, Uswz);
    hipLaunchKernelGGL(scores_part<true>, dim3(NB * 2), dim3(512), 0, stream,
                       mem, lastm, U, W, V, l_ws, Uswz, scores);
  } else {
    hipLaunchKernelGGL(scores_part<false>, dim3(NB * 2), dim3(512), 0, stream,
                       mem, lastm, U, W, V, (const float*)nullptr, (const _Float16*)nullptr, scores);
  }
  hipLaunchKernelGGL(softmax_pool_project, dim3(NB), dim3(512), 0, stream,
                     scores, mem, MetaW, Metab, out);
}

// Round 6
// 218.694 us; speedup vs baseline: 1.1282x; 1.0540x over previous
//
#include <hip/hip_runtime.h>
#include <hip/hip_bf16.h>
#include <math.h>

#define NB 512
#define NS 200
#define NH 256
#define TILE_S 32
#define LDSPAD 8
#define LDW (NH + LDSPAD)        // 264 f16 row stride

// ws float-offset layout
#define OFF_SCORES 0                               // 512*200 floats = 400 KB
#define OFF_L    (NB * NS)                         // l: 512*256 floats
#define OFF_UB   (OFF_L + NB * NH)                 // U-fp16 swizzled (32768 floats)
#define WS_FLOATS_PRE  (OFF_UB + (NH * NH) / 2)

typedef _Float16 f16x8 __attribute__((ext_vector_type(8)));
typedef float    f32x4 __attribute__((ext_vector_type(4)));

// DPP-based add within each 16-lane row (VALU, not LDS port).
template<int CTRL>
__device__ __forceinline__ float dpp_xadd(float v) {
  return v + __int_as_float(
      __builtin_amdgcn_update_dpp(0, __float_as_int(v), CTRL, 0xf, 0xf, true));
}
// full 16-lane sum: quad_perm[1,0,3,2]=0xB1, quad_perm[2,3,0,1]=0x4E,
// row_ror:4=0x124, row_ror:8=0x128  (HW-verified in R2)
__device__ __forceinline__ float row16_sum(float v) {
  v = dpp_xadd<0xB1>(v);
  v = dpp_xadd<0x4E>(v);
  v = dpp_xadd<0x124>(v);
  v = dpp_xadd<0x128>(v);
  return v;
}

// ---------------- Kernel 0: precompute l = lastm@W^T (fp32) and swizzled fp16 U ----
__global__ __launch_bounds__(256)
void precompute(const float* __restrict__ lastm, const float* __restrict__ W,
                const float* __restrict__ U,
                float* __restrict__ l_ws, _Float16* __restrict__ Uswz)
{
  const int t = threadIdx.x;
  if (blockIdx.x < NB) {
    const int b = blockIdx.x;
    __shared__ float lm_sm[NH];
    lm_sm[t] = lastm[(size_t)b * NH + t];
    __syncthreads();
    const float4* wrow = (const float4*)(W + (size_t)t * NH);
    const float4* lrow = (const float4*)lm_sm;
    float a0 = 0.f, a1 = 0.f, a2 = 0.f, a3 = 0.f;
#pragma unroll 8
    for (int i = 0; i < NH / 4; ++i) {
      float4 w4 = wrow[i];
      float4 m4 = lrow[i];
      a0 = fmaf(w4.x, m4.x, a0);
      a1 = fmaf(w4.y, m4.y, a1);
      a2 = fmaf(w4.z, m4.z, a2);
      a3 = fmaf(w4.w, m4.w, a3);
    }
    l_ws[(size_t)b * NH + t] = (a0 + a1) + (a2 + a3);
  } else {
    const int id    = (blockIdx.x - NB) * 256 + t;   // 8192 frags
    const int n_blk = id >> 9;
    const int kk    = (id >> 6) & 7;
    const int lane  = id & 63;
    const int row   = n_blk * 16 + (lane & 15);
    const int col   = kk * 32 + (lane >> 4) * 8;
    const float4* s = (const float4*)(U + (size_t)row * NH + col);
    const float4 a = s[0], c = s[1];
    f16x8 pk;
    pk[0] = (_Float16)a.x; pk[1] = (_Float16)a.y;
    pk[2] = (_Float16)a.z; pk[3] = (_Float16)a.w;
    pk[4] = (_Float16)c.x; pk[5] = (_Float16)c.y;
    pk[6] = (_Float16)c.z; pk[7] = (_Float16)c.w;
    *(f16x8*)(Uswz + (size_t)id * 8) = pk;
  }
}

#define CVT_HL(idx, val) { const float x_ = (val); const _Float16 h_ = (_Float16)x_; \
                           ph[idx] = h_; pl[idx] = (_Float16)(x_ - (float)h_); }

// ---------------- Kernel A: scores[b,s] = V . tanh(mem[b,s]@U^T + l[b]) ----------
// 512 threads = 8 waves x 32 n-cols. Single-buffer hi/lo LDS + register prefetch
// of tile t+1 (16 VGPR) -> HBM latency hidden under MFMA+tanh.
// __launch_bounds__(512, 2): the 2nd arg is MIN BLOCKS PER CU (CUDA semantics) —
// measured: (512,4) capped VGPR at 64 (=8 waves/SIMD) and spilled ~32 regs
// (68 MB scratch WRITE_SIZE, R2/R3/R5); (512,2) -> 4 waves/SIMD -> 128-reg cap,
// which fits the ~125-reg live set (u_frag 64 + pf 16 + acc 16 + temps).
template<bool PRE>
__global__ __launch_bounds__(512, 2)
void scores_part(const float* __restrict__ mem,    // [B,S,H]
                 const float* __restrict__ lastm,  // [B,H]
                 const float* __restrict__ U,      // [H,H] fp32 (fallback)
                 const float* __restrict__ W,      // [H,H] (fallback)
                 const float* __restrict__ V,      // [H]
                 const float* __restrict__ l_ws,   // [B,H] (PRE)
                 const _Float16* __restrict__ Uswz,// swizzled fp16 U (PRE)
                 float* __restrict__ scores)       // [B,S]
{
  const int b    = blockIdx.x >> 1;
  const int half = blockIdx.x & 1;
  const int s_begin = half ? 96 : 0;
  const int s_end   = half ? NS : 96;
  const int ntiles  = half ? 4 : 3;

  const int t     = threadIdx.x;   // 0..511
  const int wave  = t >> 6;        // 0..7: owns n-cols [wave*32, wave*32+32)
  const int lane  = t & 63;
  const int m16   = lane & 15;
  const int quad  = lane >> 4;

  __shared__ __align__(16) _Float16 hi_sm[TILE_S][LDW];  // 16.9 KB
  __shared__ __align__(16) _Float16 lo_sm[TILE_S][LDW];  // 16.9 KB
  __shared__ float swave_sm[8][TILE_S];

  // per-thread l/V for this wave's 2 n-fragments
  float l_reg[2], v_reg[2];
  if constexpr (!PRE) {
    __shared__ float l_sm[NH];
    __shared__ float lm_sm[NH];
    if (t < NH) lm_sm[t] = lastm[(size_t)b * NH + t];
    __syncthreads();
    if (t < NH) {
      const float4* wrow = (const float4*)(W + (size_t)t * NH);
      const float4* lrow = (const float4*)lm_sm;
      float a0 = 0.f, a1 = 0.f, a2 = 0.f, a3 = 0.f;
#pragma unroll 8
      for (int i = 0; i < NH / 4; ++i) {
        float4 w4 = wrow[i];
        float4 m4 = lrow[i];
        a0 = fmaf(w4.x, m4.x, a0);
        a1 = fmaf(w4.y, m4.y, a1);
        a2 = fmaf(w4.z, m4.z, a2);
        a3 = fmaf(w4.w, m4.w, a3);
      }
      l_sm[t] = (a0 + a1) + (a2 + a3);
    }
    __syncthreads();
#pragma unroll
    for (int nf = 0; nf < 2; ++nf)
      l_reg[nf] = l_sm[wave * 32 + nf * 16 + m16];
  } else {
#pragma unroll
    for (int nf = 0; nf < 2; ++nf)
      l_reg[nf] = l_ws[(size_t)b * NH + wave * 32 + nf * 16 + m16];
  }
#pragma unroll
  for (int nf = 0; nf < 2; ++nf)
    v_reg[nf] = V[wave * 32 + nf * 16 + m16];
  const float vsum  = v_reg[0] + v_reg[1];
  const float vm2_0 = -2.f * v_reg[0];
  const float vm2_1 = -2.f * v_reg[1];

  // ---- U B-fragments in registers for the whole kernel: 2 nf x 8 kk = 64 VGPR ----
  f16x8 u_frag[2][8];
  if constexpr (PRE) {
    const _Float16* uw = Uswz + ((size_t)(wave * 2 * 8 * 64) + lane) * 8;
#pragma unroll
    for (int nf = 0; nf < 2; ++nf)
#pragma unroll
      for (int kk = 0; kk < 8; ++kk)
        u_frag[nf][kk] = *(const f16x8*)(uw + (size_t)((nf * 8 + kk) << 9));
  } else {
#pragma unroll
    for (int nf = 0; nf < 2; ++nf) {
      const int n = wave * 32 + nf * 16 + m16;
      const float* urow = U + (size_t)n * NH;
#pragma unroll
      for (int kk = 0; kk < 8; ++kk) {
        const float4 lo = *(const float4*)(urow + kk * 32 + quad * 8);
        const float4 hi = *(const float4*)(urow + kk * 32 + quad * 8 + 4);
        f16x8 f;
        f[0] = (_Float16)lo.x; f[1] = (_Float16)lo.y;
        f[2] = (_Float16)lo.z; f[3] = (_Float16)lo.w;
        f[4] = (_Float16)hi.x; f[5] = (_Float16)hi.y;
        f[6] = (_Float16)hi.z; f[7] = (_Float16)hi.w;
        u_frag[nf][kk] = f;
      }
    }
  }

  // ---- prologue: stage tile 0 (full 32 rows always valid) ----
  {
    const float4* src4 = (const float4*)(mem + ((size_t)b * NS + s_begin) * NH);
    const int f0 = t, f1 = 512 + t;
    const float4 a0 = src4[f0 * 2], a1 = src4[f0 * 2 + 1];
    const float4 b0 = src4[f1 * 2], b1 = src4[f1 * 2 + 1];
    {
      f16x8 ph, pl;
      CVT_HL(0, a0.x) CVT_HL(1, a0.y) CVT_HL(2, a0.z) CVT_HL(3, a0.w)
      CVT_HL(4, a1.x) CVT_HL(5, a1.y) CVT_HL(6, a1.z) CVT_HL(7, a1.w)
      *(f16x8*)&hi_sm[f0 >> 5][(f0 & 31) * 8] = ph;
      *(f16x8*)&lo_sm[f0 >> 5][(f0 & 31) * 8] = pl;
    }
    {
      f16x8 ph, pl;
      CVT_HL(0, b0.x) CVT_HL(1, b0.y) CVT_HL(2, b0.z) CVT_HL(3, b0.w)
      CVT_HL(4, b1.x) CVT_HL(5, b1.y) CVT_HL(6, b1.z) CVT_HL(7, b1.w)
      *(f16x8*)&hi_sm[f1 >> 5][(f1 & 31) * 8] = ph;
      *(f16x8*)&lo_sm[f1 >> 5][(f1 & 31) * 8] = pl;
    }
  }
  __syncthreads();

  for (int tile = 0; tile < ntiles; ++tile) {
    const int s0 = s_begin + tile * TILE_S;
    const int rows_next = (tile + 1 < ntiles) ? min(TILE_S, s_end - (s0 + TILE_S)) : 0;

    // ---- prefetch issue for tile t+1 (regs; written to LDS after the barrier) ----
    float4 p00, p01, p10, p11;
    const bool ld0 = (t >> 5) < rows_next;          // rows 0..15
    const bool ld1 = ((512 + t) >> 5) < rows_next;  // rows 16..31
    {
      const float4* nsrc = (const float4*)(mem + ((size_t)b * NS + s0 + TILE_S) * NH);
      if (ld0) { p00 = nsrc[t * 2];         p01 = nsrc[t * 2 + 1]; }
      if (ld1) { p10 = nsrc[(512 + t) * 2]; p11 = nsrc[(512 + t) * 2 + 1]; }
    }

    // ---- MFMA: 32 rows x 32 n-cols per wave; hi+lo into same acc ----
    f32x4 acc[2][2];
    const f32x4 fzero = {0.f, 0.f, 0.f, 0.f};
#pragma unroll
    for (int mt = 0; mt < 2; ++mt)
#pragma unroll
      for (int nf = 0; nf < 2; ++nf)
        acc[mt][nf] = fzero;

#pragma unroll
    for (int kk = 0; kk < 8; ++kk) {
      const int c = kk * 32 + quad * 8;
      f16x8 a0h = *(const f16x8*)&hi_sm[m16][c];
      f16x8 a1h = *(const f16x8*)&hi_sm[16 + m16][c];
      f16x8 a0l = *(const f16x8*)&lo_sm[m16][c];
      f16x8 a1l = *(const f16x8*)&lo_sm[16 + m16][c];
#pragma unroll
      for (int nf = 0; nf < 2; ++nf) {
        acc[0][nf] = __builtin_amdgcn_mfma_f32_16x16x32_f16(a0h, u_frag[nf][kk], acc[0][nf], 0, 0, 0);
        acc[1][nf] = __builtin_amdgcn_mfma_f32_16x16x32_f16(a1h, u_frag[nf][kk], acc[1][nf], 0, 0, 0);
        acc[0][nf] = __builtin_amdgcn_mfma_f32_16x16x32_f16(a0l, u_frag[nf][kk], acc[0][nf], 0, 0, 0);
        acc[1][nf] = __builtin_amdgcn_mfma_f32_16x16x32_f16(a1l, u_frag[nf][kk], acc[1][nf], 0, 0, 0);
      }
    }

    // ---- p = vsum + sum_nf (-2 v[nf]) / (e^{2x}+1) (tanh identity), DPP n-reduce ----
#pragma unroll
    for (int mt = 0; mt < 2; ++mt) {
#pragma unroll
      for (int reg = 0; reg < 4; ++reg) {
        const float x0 = acc[mt][0][reg] + l_reg[0];
        const float x1 = acc[mt][1][reg] + l_reg[1];
        const float e0 = __expf(x0 + x0);
        const float e1 = __expf(x1 + x1);
        float s = vsum;
        s += __fdividef(vm2_0, e0 + 1.f);
        s += __fdividef(vm2_1, e1 + 1.f);
        s = row16_sum(s);
        if (m16 == 0)
          swave_sm[wave][mt * 16 + quad * 4 + reg] = s;
      }
    }
    __syncthreads();  // swave ready; all LDS reads of current tile done

    // ---- score write (32 lanes) || staging write of tile t+1 (all waves) ----
    if (t < TILE_S) {
      const int s_idx = s0 + t;
      if (s_idx < s_end) {
        float s = swave_sm[0][t];
#pragma unroll
        for (int w = 1; w < 8; ++w) s += swave_sm[w][t];
        scores[(size_t)b * NS + s_idx] = s;
      }
    }
    if (ld0) {
      f16x8 ph, pl;
      CVT_HL(0, p00.x) CVT_HL(1, p00.y) CVT_HL(2, p00.z) CVT_HL(3, p00.w)
      CVT_HL(4, p01.x) CVT_HL(5, p01.y) CVT_HL(6, p01.z) CVT_HL(7, p01.w)
      *(f16x8*)&hi_sm[t >> 5][(t & 31) * 8] = ph;
      *(f16x8*)&lo_sm[t >> 5][(t & 31) * 8] = pl;
    }
    if (ld1) {
      f16x8 ph, pl;
      CVT_HL(0, p10.x) CVT_HL(1, p10.y) CVT_HL(2, p10.z) CVT_HL(3, p10.w)
      CVT_HL(4, p11.x) CVT_HL(5, p11.y) CVT_HL(6, p11.z) CVT_HL(7, p11.w)
      *(f16x8*)&hi_sm[(512 + t) >> 5][(t & 31) * 8] = ph;
      *(f16x8*)&lo_sm[(512 + t) >> 5][(t & 31) * 8] = pl;
    }
    __syncthreads();  // next tile staged
  }
}

// ---------------- Kernel B: softmax(scores) -> pooled (fp32 mem) -> project ----
__global__ __launch_bounds__(512)
void softmax_pool_project(const float* __restrict__ scores, // [B,S]
                          const float* __restrict__ mem,    // [B,S,H]
                          const float* __restrict__ MetaW,  // [4,H]
                          const float* __restrict__ Metab,  // [4]
                          float* __restrict__ out)          // [B,4]
{
  const int b    = blockIdx.x;
  const int t    = threadIdx.x;   // 0..511
  const int wave = t >> 6;
  const int lane = t & 63;

  __shared__ float alpha_sm[256];
  __shared__ float red_sm[8];
  __shared__ __align__(16) float comb_sm[8][NH];
  __shared__ float pooled_sm[NH];

  // scores -> LDS
  float sv = -INFINITY;
  if (t < NS) sv = scores[(size_t)b * NS + t];
  if (t < 256) alpha_sm[t] = sv;

  // block max
  float mv = sv;
#pragma unroll
  for (int off = 1; off < 64; off <<= 1)
    mv = fmaxf(mv, __shfl_xor(mv, off));
  if (lane == 0) red_sm[wave] = mv;
  __syncthreads();
  float m = red_sm[0];
#pragma unroll
  for (int w = 1; w < 8; ++w) m = fmaxf(m, red_sm[w]);

  // e + block sum
  const float e = (t < NS) ? __expf(sv - m) : 0.f;
  float zv = e;
#pragma unroll
  for (int off = 1; off < 64; off <<= 1)
    zv += __shfl_xor(zv, off);
  __syncthreads();          // red_sm reuse
  if (lane == 0) red_sm[wave] = zv;
  if (t < 256) alpha_sm[t] = e;
  __syncthreads();
  float Z = red_sm[0];
#pragma unroll
  for (int w = 1; w < 8; ++w) Z += red_sm[w];
  const float Zi = 1.f / Z;

  // pooled: row-group rg = t>>6 handles rows s = rg, rg+8, ...; cols (t&63)*4
  const int rg = wave;
  const float4* m4 = (const float4*)(mem + (size_t)b * NS * NH);
  f32x4 acc = {0.f, 0.f, 0.f, 0.f};
#pragma unroll 5
  for (int s = rg; s < NS; s += 8) {
    const float a = alpha_sm[s];
    const float4 x = m4[s * 64 + lane];
    acc[0] = fmaf(a, x.x, acc[0]);
    acc[1] = fmaf(a, x.y, acc[1]);
    acc[2] = fmaf(a, x.z, acc[2]);
    acc[3] = fmaf(a, x.w, acc[3]);
  }
  *(f32x4*)&comb_sm[rg][lane * 4] = acc;
  __syncthreads();

  if (t < NH) {
    float p = 0.f;
#pragma unroll
    for (int r = 0; r < 8; ++r) p += comb_sm[r][t];
    pooled_sm[t] = p * Zi;
  }
  __syncthreads();

  // project: waves 0..3 -> out rows
  if (t < 256) {
    float s = 0.f;
#pragma unroll
    for (int i = 0; i < 4; ++i) {
      const int h = i * 64 + lane;
      s = fmaf(pooled_sm[h], MetaW[(size_t)wave * NH + h], s);
    }
#pragma unroll
    for (int off = 32; off > 0; off >>= 1)
      s += __shfl_down(s, off);
    if (lane == 0)
      out[b * 4 + wave] = s + Metab[wave];
  }
}

extern "C" void kernel_launch(void* const* d_in, const int* in_sizes, int n_in,
                              void* d_out, int out_size, void* d_ws, size_t ws_size,
                              hipStream_t stream) {
  const float* mem   = (const float*)d_in[0];
  const float* lastm = (const float*)d_in[1];
  const float* U     = (const float*)d_in[2];
  const float* W     = (const float*)d_in[3];
  const float* V     = (const float*)d_in[4];
  const float* MetaW = (const float*)d_in[5];
  const float* Metab = (const float*)d_in[6];
  float* out = (float*)d_out;
  float* ws  = (float*)d_ws;

  float* scores = ws + OFF_SCORES;

  if (ws_size >= (size_t)WS_FLOATS_PRE * sizeof(float)) {
    float*    l_ws = ws + OFF_L;
    _Float16* Uswz = (_Float16*)(ws + OFF_UB);
    hipLaunchKernelGGL(precompute, dim3(NB + 32), dim3(256), 0, stream,
                       lastm, W, U, l_ws, Uswz);
    hipLaunchKernelGGL(scores_part<true>, dim3(NB * 2), dim3(512), 0, stream,
                       mem, lastm, U, W, V, l_ws, Uswz, scores);
  } else {
    hipLaunchKernelGGL(scores_part<false>, dim3(NB * 2), dim3(512), 0, stream,
                       mem, lastm, U, W, V, (const float*)nullptr, (const _Float16*)nullptr, scores);
  }
  hipLaunchKernelGGL(softmax_pool_project, dim3(NB), dim3(512), 0, stream,
                     scores, mem, MetaW, Metab, out);
}

// Round 7
// 200.694 us; speedup vs baseline: 1.2294x; 1.0897x over previous
//
#include <hip/hip_runtime.h>
#include <hip/hip_bf16.h>
#include <math.h>

#define NB 512
#define NS 200
#define NH 256
#define TILE_S 32
#define LDSPAD 8
#define LDW (NH + LDSPAD)        // 264 f16 row stride

// ws float-offset layout (l + swizzled fp16 U only; no scores/partials)
#define OFF_L    0                                 // l: 512*256 floats
#define OFF_UB   (NB * NH)                         // U-fp16 swizzled (32768 floats)
#define WS_FLOATS_PRE  (OFF_UB + (NH * NH) / 2)    // 655 KB

typedef _Float16 f16x8 __attribute__((ext_vector_type(8)));
typedef float    f32x4 __attribute__((ext_vector_type(4)));

// DPP-based add within each 16-lane row (VALU, not LDS port).
template<int CTRL>
__device__ __forceinline__ float dpp_xadd(float v) {
  return v + __int_as_float(
      __builtin_amdgcn_update_dpp(0, __float_as_int(v), CTRL, 0xf, 0xf, true));
}
// full 16-lane sum: quad_perm[1,0,3,2]=0xB1, quad_perm[2,3,0,1]=0x4E,
// row_ror:4=0x124, row_ror:8=0x128  (HW-verified in R2)
__device__ __forceinline__ float row16_sum(float v) {
  v = dpp_xadd<0xB1>(v);
  v = dpp_xadd<0x4E>(v);
  v = dpp_xadd<0x124>(v);
  v = dpp_xadd<0x128>(v);
  return v;
}

// ---------------- Kernel 0: precompute l = lastm@W^T (fp32) and swizzled fp16 U ----
__global__ __launch_bounds__(256)
void precompute(const float* __restrict__ lastm, const float* __restrict__ W,
                const float* __restrict__ U,
                float* __restrict__ l_ws, _Float16* __restrict__ Uswz)
{
  const int t = threadIdx.x;
  if (blockIdx.x < NB) {
    const int b = blockIdx.x;
    __shared__ float lm_sm[NH];
    lm_sm[t] = lastm[(size_t)b * NH + t];
    __syncthreads();
    const float4* wrow = (const float4*)(W + (size_t)t * NH);
    const float4* lrow = (const float4*)lm_sm;
    float a0 = 0.f, a1 = 0.f, a2 = 0.f, a3 = 0.f;
#pragma unroll 8
    for (int i = 0; i < NH / 4; ++i) {
      float4 w4 = wrow[i];
      float4 m4 = lrow[i];
      a0 = fmaf(w4.x, m4.x, a0);
      a1 = fmaf(w4.y, m4.y, a1);
      a2 = fmaf(w4.z, m4.z, a2);
      a3 = fmaf(w4.w, m4.w, a3);
    }
    l_ws[(size_t)b * NH + t] = (a0 + a1) + (a2 + a3);
  } else {
    const int id    = (blockIdx.x - NB) * 256 + t;   // 8192 frags
    const int n_blk = id >> 9;
    const int kk    = (id >> 6) & 7;
    const int lane  = id & 63;
    const int row   = n_blk * 16 + (lane & 15);
    const int col   = kk * 32 + (lane >> 4) * 8;
    const float4* s = (const float4*)(U + (size_t)row * NH + col);
    const float4 a = s[0], c = s[1];
    f16x8 pk;
    pk[0] = (_Float16)a.x; pk[1] = (_Float16)a.y;
    pk[2] = (_Float16)a.z; pk[3] = (_Float16)a.w;
    pk[4] = (_Float16)c.x; pk[5] = (_Float16)c.y;
    pk[6] = (_Float16)c.z; pk[7] = (_Float16)c.w;
    *(f16x8*)(Uswz + (size_t)id * 8) = pk;
  }
}

#define CVT_HL(idx, val) { const float x_ = (val); const _Float16 h_ = (_Float16)x_; \
                           ph[idx] = h_; pl[idx] = (_Float16)(x_ - (float)h_); }

// ---------------- Kernel A: fully fused attention pool + projection per b -------
// grid 512 = one block per b, 512 threads = 8 waves x 32 n-cols, 7 tiles of 32.
// __launch_bounds__(512, 2): 2nd arg is MIN BLOCKS PER CU (measured R2/R3/R5:
// (512,4) caps VGPR at 64 and spills ~32 regs -> 68-121 MB scratch; (512,2)
// gives the 128-reg cap that fits this live set, R6: VGPR=80, no spill).
// Double-buffered hi/lo fp16 LDS (69 KB -> 2 blocks/CU), register prefetch of
// tile t+1, DPP score reduce, online softmax (wave0) overlapped with staging,
// pooled from fp16-hi (2^-11 -> ~2e-4 output err vs 6.4e-3 thr), epilogue
// projects pooled@MetaW^T directly to out — no kernel B, no merge kernel.
template<bool PRE>
__global__ __launch_bounds__(512, 2)
void fused_attn(const float* __restrict__ mem,    // [B,S,H]
                const float* __restrict__ lastm,  // [B,H]
                const float* __restrict__ U,      // [H,H] fp32 (fallback)
                const float* __restrict__ W,      // [H,H] (fallback)
                const float* __restrict__ V,      // [H]
                const float* __restrict__ l_ws,   // [B,H] (PRE)
                const _Float16* __restrict__ Uswz,// swizzled fp16 U (PRE)
                const float* __restrict__ MetaW,  // [4,H]
                const float* __restrict__ Metab,  // [4]
                float* __restrict__ out)          // [B,4]
{
  const int b = blockIdx.x;
  const int ntiles = 7;            // ceil(200/32); tile 6 has 8 valid rows

  const int t     = threadIdx.x;   // 0..511
  const int wave  = t >> 6;        // 0..7: owns n-cols [wave*32, wave*32+32)
  const int lane  = t & 63;
  const int m16   = lane & 15;
  const int quad  = lane >> 4;
  const int g     = t >> 5;        // 0..15: pooled row-pair {2g, 2g+1}
  const int hblk  = (t & 31) * 8;  // pooled: 8 h-cols

  __shared__ __align__(16) _Float16 hi_sm[2][TILE_S][LDW];  // 33.8 KB
  __shared__ __align__(16) _Float16 lo_sm[2][TILE_S][LDW];  // 33.8 KB
  __shared__ float swave_sm[8][TILE_S];
  __shared__ float e_sm[TILE_S];
  __shared__ float mz_sm[2];

  // per-thread l/V for this wave's 2 n-fragments
  float l_reg[2], v_reg[2];
  if constexpr (!PRE) {
    __shared__ float l_sm[NH];
    __shared__ float lm_sm[NH];
    if (t < NH) lm_sm[t] = lastm[(size_t)b * NH + t];
    __syncthreads();
    if (t < NH) {
      const float4* wrow = (const float4*)(W + (size_t)t * NH);
      const float4* lrow = (const float4*)lm_sm;
      float a0 = 0.f, a1 = 0.f, a2 = 0.f, a3 = 0.f;
#pragma unroll 8
      for (int i = 0; i < NH / 4; ++i) {
        float4 w4 = wrow[i];
        float4 m4 = lrow[i];
        a0 = fmaf(w4.x, m4.x, a0);
        a1 = fmaf(w4.y, m4.y, a1);
        a2 = fmaf(w4.z, m4.z, a2);
        a3 = fmaf(w4.w, m4.w, a3);
      }
      l_sm[t] = (a0 + a1) + (a2 + a3);
    }
    __syncthreads();
#pragma unroll
    for (int nf = 0; nf < 2; ++nf)
      l_reg[nf] = l_sm[wave * 32 + nf * 16 + m16];
  } else {
#pragma unroll
    for (int nf = 0; nf < 2; ++nf)
      l_reg[nf] = l_ws[(size_t)b * NH + wave * 32 + nf * 16 + m16];
  }
#pragma unroll
  for (int nf = 0; nf < 2; ++nf)
    v_reg[nf] = V[wave * 32 + nf * 16 + m16];
  const float vsum  = v_reg[0] + v_reg[1];
  const float vm2_0 = -2.f * v_reg[0];
  const float vm2_1 = -2.f * v_reg[1];

  // ---- U B-fragments in registers for the whole kernel: 2 nf x 8 kk = 64 VGPR ----
  f16x8 u_frag[2][8];
  if constexpr (PRE) {
    const _Float16* uw = Uswz + ((size_t)(wave * 2 * 8 * 64) + lane) * 8;
#pragma unroll
    for (int nf = 0; nf < 2; ++nf)
#pragma unroll
      for (int kk = 0; kk < 8; ++kk)
        u_frag[nf][kk] = *(const f16x8*)(uw + (size_t)((nf * 8 + kk) << 9));
  } else {
#pragma unroll
    for (int nf = 0; nf < 2; ++nf) {
      const int n = wave * 32 + nf * 16 + m16;
      const float* urow = U + (size_t)n * NH;
#pragma unroll
      for (int kk = 0; kk < 8; ++kk) {
        const float4 lo = *(const float4*)(urow + kk * 32 + quad * 8);
        const float4 hi = *(const float4*)(urow + kk * 32 + quad * 8 + 4);
        f16x8 f;
        f[0] = (_Float16)lo.x; f[1] = (_Float16)lo.y;
        f[2] = (_Float16)lo.z; f[3] = (_Float16)lo.w;
        f[4] = (_Float16)hi.x; f[5] = (_Float16)hi.y;
        f[6] = (_Float16)hi.z; f[7] = (_Float16)hi.w;
        u_frag[nf][kk] = f;
      }
    }
  }

  // ---- prologue: stage tile 0 into buffer 0 (full 32 rows valid) ----
  {
    const float4* src4 = (const float4*)(mem + (size_t)b * NS * NH);
    const int f0 = t, f1 = 512 + t;
    const float4 a0 = src4[f0 * 2], a1 = src4[f0 * 2 + 1];
    const float4 b0 = src4[f1 * 2], b1 = src4[f1 * 2 + 1];
    {
      f16x8 ph, pl;
      CVT_HL(0, a0.x) CVT_HL(1, a0.y) CVT_HL(2, a0.z) CVT_HL(3, a0.w)
      CVT_HL(4, a1.x) CVT_HL(5, a1.y) CVT_HL(6, a1.z) CVT_HL(7, a1.w)
      *(f16x8*)&hi_sm[0][f0 >> 5][(f0 & 31) * 8] = ph;
      *(f16x8*)&lo_sm[0][f0 >> 5][(f0 & 31) * 8] = pl;
    }
    {
      f16x8 ph, pl;
      CVT_HL(0, b0.x) CVT_HL(1, b0.y) CVT_HL(2, b0.z) CVT_HL(3, b0.w)
      CVT_HL(4, b1.x) CVT_HL(5, b1.y) CVT_HL(6, b1.z) CVT_HL(7, b1.w)
      *(f16x8*)&hi_sm[0][f1 >> 5][(f1 & 31) * 8] = ph;
      *(f16x8*)&lo_sm[0][f1 >> 5][(f1 & 31) * 8] = pl;
    }
  }
  __syncthreads();

  float m_run = -INFINITY;
  float Z     = 0.f;
  float pooledv[8];
#pragma unroll
  for (int j = 0; j < 8; ++j) pooledv[j] = 0.f;

  for (int tile = 0; tile < ntiles; ++tile) {
    const int cur = tile & 1;
    const int nxt = cur ^ 1;
    const int s0  = tile * TILE_S;
    const int rows = min(TILE_S, NS - s0);
    const int rows_next = (tile + 1 < ntiles) ? min(TILE_S, NS - (s0 + TILE_S)) : 0;

    // ---- prefetch issue for tile t+1 (regs; written to LDS after bar1) ----
    float4 p00, p01, p10, p11;
    const bool ld0 = (t >> 5) < rows_next;          // rows 0..15
    const bool ld1 = 16 + (t >> 5) < rows_next;     // rows 16..31
    {
      const float4* nsrc = (const float4*)(mem + ((size_t)b * NS + s0 + TILE_S) * NH);
      if (ld0) { p00 = nsrc[t * 2];         p01 = nsrc[t * 2 + 1]; }
      if (ld1) { p10 = nsrc[(512 + t) * 2]; p11 = nsrc[(512 + t) * 2 + 1]; }
    }

    // ---- MFMA: 32 rows x 32 n-cols per wave; hi+lo into same acc ----
    f32x4 acc[2][2];
    const f32x4 fzero = {0.f, 0.f, 0.f, 0.f};
#pragma unroll
    for (int mt = 0; mt < 2; ++mt)
#pragma unroll
      for (int nf = 0; nf < 2; ++nf)
        acc[mt][nf] = fzero;

#pragma unroll
    for (int kk = 0; kk < 8; ++kk) {
      const int c = kk * 32 + quad * 8;
      f16x8 a0h = *(const f16x8*)&hi_sm[cur][m16][c];
      f16x8 a1h = *(const f16x8*)&hi_sm[cur][16 + m16][c];
      f16x8 a0l = *(const f16x8*)&lo_sm[cur][m16][c];
      f16x8 a1l = *(const f16x8*)&lo_sm[cur][16 + m16][c];
#pragma unroll
      for (int nf = 0; nf < 2; ++nf) {
        acc[0][nf] = __builtin_amdgcn_mfma_f32_16x16x32_f16(a0h, u_frag[nf][kk], acc[0][nf], 0, 0, 0);
        acc[1][nf] = __builtin_amdgcn_mfma_f32_16x16x32_f16(a1h, u_frag[nf][kk], acc[1][nf], 0, 0, 0);
        acc[0][nf] = __builtin_amdgcn_mfma_f32_16x16x32_f16(a0l, u_frag[nf][kk], acc[0][nf], 0, 0, 0);
        acc[1][nf] = __builtin_amdgcn_mfma_f32_16x16x32_f16(a1l, u_frag[nf][kk], acc[1][nf], 0, 0, 0);
      }
    }

    // ---- p = vsum + sum_nf (-2 v[nf]) / (e^{2x}+1) (tanh identity), DPP n-reduce ----
#pragma unroll
    for (int mt = 0; mt < 2; ++mt) {
#pragma unroll
      for (int reg = 0; reg < 4; ++reg) {
        const float x0 = acc[mt][0][reg] + l_reg[0];
        const float x1 = acc[mt][1][reg] + l_reg[1];
        const float e0 = __expf(x0 + x0);
        const float e1 = __expf(x1 + x1);
        float s = vsum;
        s += __fdividef(vm2_0, e0 + 1.f);
        s += __fdividef(vm2_1, e1 + 1.f);
        s = row16_sum(s);
        if (m16 == 0)
          swave_sm[wave][mt * 16 + quad * 4 + reg] = s;
      }
    }
    __syncthreads();  // bar1: swave ready; current-tile LDS reads done

    // ---- wave0 lanes 0..31: scores -> m, e[], z (overlapped with staging) ----
    if (t < TILE_S) {
      float s = swave_sm[0][t];
#pragma unroll
      for (int w = 1; w < 8; ++w) s += swave_sm[w][t];
      const float sv = (t < rows) ? s : -INFINITY;
      float mt_ = sv;
#pragma unroll
      for (int off = 1; off < 32; off <<= 1)
        mt_ = fmaxf(mt_, __shfl_xor(mt_, off));
      const float m_new = fmaxf(m_run, mt_);
      float e = (t < rows) ? __expf(sv - m_new) : 0.f;
      e_sm[t] = e;
      float z = e;
#pragma unroll
      for (int off = 1; off < 32; off <<= 1)
        z += __shfl_xor(z, off);
      if (t == 0) { mz_sm[0] = m_new; mz_sm[1] = z; }
    }

    // ---- all waves: write prefetched tile t+1 into the other buffer ----
    if (ld0) {
      f16x8 ph, pl;
      CVT_HL(0, p00.x) CVT_HL(1, p00.y) CVT_HL(2, p00.z) CVT_HL(3, p00.w)
      CVT_HL(4, p01.x) CVT_HL(5, p01.y) CVT_HL(6, p01.z) CVT_HL(7, p01.w)
      *(f16x8*)&hi_sm[nxt][t >> 5][(t & 31) * 8] = ph;
      *(f16x8*)&lo_sm[nxt][t >> 5][(t & 31) * 8] = pl;
    }
    if (ld1) {
      f16x8 ph, pl;
      CVT_HL(0, p10.x) CVT_HL(1, p10.y) CVT_HL(2, p10.z) CVT_HL(3, p10.w)
      CVT_HL(4, p11.x) CVT_HL(5, p11.y) CVT_HL(6, p11.z) CVT_HL(7, p11.w)
      *(f16x8*)&hi_sm[nxt][16 + (t >> 5)][(t & 31) * 8] = ph;
      *(f16x8*)&lo_sm[nxt][16 + (t >> 5)][(t & 31) * 8] = pl;
    }
    __syncthreads();  // bar2: e_sm/mz ready

    // ---- pooled: thread owns 8 h-cols x 2 rows; e broadcast + 2x b128 reads ----
    const float m_new = mz_sm[0];
    const float z_new = mz_sm[1];
    const float fac   = __expf(m_run - m_new);
    m_run = m_new;
    Z = fmaf(Z, fac, z_new);

    const float e0 = e_sm[2 * g];
    const float e1 = e_sm[2 * g + 1];
    const f16x8 r0 = *(const f16x8*)&hi_sm[cur][2 * g][hblk];
    const f16x8 r1 = *(const f16x8*)&hi_sm[cur][2 * g + 1][hblk];
#pragma unroll
    for (int j = 0; j < 8; ++j)
      pooledv[j] = fmaf(e0, (float)r0[j], fmaf(e1, (float)r1[j], pooledv[j] * fac));
    __syncthreads();  // bar3: pooled reads of buf cur done before next staging
  }

  // ---- epilogue: combine 16 row-pair replicas, normalize, project to out ----
  float* scratch = (float*)&hi_sm[0][0][0];     // 16 x 264 f32 = 16896 B, fits
  float* pooled_sm = (float*)&lo_sm[0][0][0];   // 256 f32
  {
    f32x4 lo4 = {pooledv[0], pooledv[1], pooledv[2], pooledv[3]};
    f32x4 hi4 = {pooledv[4], pooledv[5], pooledv[6], pooledv[7]};
    *(f32x4*)&scratch[g * 264 + hblk]     = lo4;
    *(f32x4*)&scratch[g * 264 + hblk + 4] = hi4;
  }
  __syncthreads();
  const float Zi = 1.f / Z;     // Z/m_run are block-uniform
  if (t < NH) {
    float p = 0.f;
#pragma unroll
    for (int r = 0; r < 16; ++r)
      p += scratch[r * 264 + t];
    pooled_sm[t] = p * Zi;
  }
  __syncthreads();
  if (t < 256) {
    float s = 0.f;
#pragma unroll
    for (int i = 0; i < 4; ++i) {
      const int h = i * 64 + lane;
      s = fmaf(pooled_sm[h], MetaW[(size_t)wave * NH + h], s);
    }
#pragma unroll
    for (int off = 32; off > 0; off >>= 1)
      s += __shfl_down(s, off);
    if (lane == 0)
      out[b * 4 + wave] = s + Metab[wave];
  }
}

extern "C" void kernel_launch(void* const* d_in, const int* in_sizes, int n_in,
                              void* d_out, int out_size, void* d_ws, size_t ws_size,
                              hipStream_t stream) {
  const float* mem   = (const float*)d_in[0];
  const float* lastm = (const float*)d_in[1];
  const float* U     = (const float*)d_in[2];
  const float* W     = (const float*)d_in[3];
  const float* V     = (const float*)d_in[4];
  const float* MetaW = (const float*)d_in[5];
  const float* Metab = (const float*)d_in[6];
  float* out = (float*)d_out;
  float* ws  = (float*)d_ws;

  if (ws_size >= (size_t)WS_FLOATS_PRE * sizeof(float)) {
    float*    l_ws = ws + OFF_L;
    _Float16* Uswz = (_Float16*)(ws + OFF_UB);
    hipLaunchKernelGGL(precompute, dim3(NB + 32), dim3(256), 0, stream,
                       lastm, W, U, l_ws, Uswz);
    hipLaunchKernelGGL(fused_attn<true>, dim3(NB), dim3(512), 0, stream,
                       mem, lastm, U, W, V, l_ws, Uswz, MetaW, Metab, out);
  } else {
    hipLaunchKernelGGL(fused_attn<false>, dim3(NB), dim3(512), 0, stream,
                       mem, lastm, U, W, V, (const float*)nullptr, (const _Float16*)nullptr,
                       MetaW, Metab, out);
  }
}